// Round 1
// baseline (634.104 us; speedup 1.0000x reference)
//
#include <hip/hip_runtime.h>
#include <math.h>

#define EPS 1.55e-05f
#define PIX 36864   // 4*96*96
#define CCH 192
#define QKVN 576

// ---------------- Kernel A: relative position bias (6 heads x 9 taps) ----------------
__global__ __launch_bounds__(512)
void relbias_kernel(const float* __restrict__ w1, const float* __restrict__ b1,
                    const float* __restrict__ w2, float* __restrict__ rb)
{
    __shared__ float hid[9][512];
    int i = threadIdx.x;
    const float s0 = -0.7739760316291208f, s2 = 0.7739760316291208f;
    float sv[3]; sv[0] = s0; sv[1] = 0.f; sv[2] = s2;
    float w1a = w1[i], w1b = w1[512 + i], bb = b1[i];
    #pragma unroll
    for (int j = 0; j < 9; j++) {
        float t0 = sv[j / 3], t1 = sv[j % 3];
        hid[j][i] = fmaxf(t0 * w1a + t1 * w1b + bb, 0.f);
    }
    __syncthreads();
    if (i < 54) {
        int he = i / 9, t = i % 9, j = 8 - t;   // bias[::-1] then transpose
        float acc = 0.f;
        for (int u = 0; u < 512; u++) acc += hid[j][u] * w2[u * 6 + he];
        rb[he * 9 + t] = 16.f / (1.f + expf(-acc));
    }
}

// ---------------- Kernel B/D: tiled fp32 GEMM, C = A(MxK) * B(KxN) + bias ----------------
// BM=BN=64, BK=32, 256 threads, 4x4 microtile. All dims divide exactly.
__global__ __launch_bounds__(256)
void gemm_bias_kernel(const float* __restrict__ A, const float* __restrict__ B,
                      float* __restrict__ C, int M, int N, int K,
                      const float* __restrict__ bias0, const float* __restrict__ bias1,
                      int bias_mode)
{
    __shared__ float As[32][64];
    __shared__ float Bs[32][64];
    int tid = threadIdx.x;
    int m0 = blockIdx.y * 64, n0 = blockIdx.x * 64;
    int tx = tid & 15, ty = tid >> 4;
    float acc[4][4];
    #pragma unroll
    for (int i = 0; i < 4; i++)
        #pragma unroll
        for (int j = 0; j < 4; j++) acc[i][j] = 0.f;

    for (int k0 = 0; k0 < K; k0 += 32) {
        int ar = tid >> 3;            // 0..31
        int ac4 = (tid & 7) * 4;      // 0..28
        #pragma unroll
        for (int rr = 0; rr < 2; rr++) {
            float4 v = *reinterpret_cast<const float4*>(&A[(size_t)(m0 + ar + rr * 32) * K + k0 + ac4]);
            As[ac4 + 0][ar + rr * 32] = v.x;
            As[ac4 + 1][ar + rr * 32] = v.y;
            As[ac4 + 2][ar + rr * 32] = v.z;
            As[ac4 + 3][ar + rr * 32] = v.w;
        }
        int br = tid >> 4;            // 0..15
        int bc4 = (tid & 15) * 4;     // 0..60
        #pragma unroll
        for (int rr = 0; rr < 2; rr++) {
            float4 v = *reinterpret_cast<const float4*>(&B[(size_t)(k0 + br + rr * 16) * N + n0 + bc4]);
            *reinterpret_cast<float4*>(&Bs[br + rr * 16][bc4]) = v;
        }
        __syncthreads();
        #pragma unroll
        for (int kk = 0; kk < 32; kk++) {
            float a[4], b[4];
            #pragma unroll
            for (int i = 0; i < 4; i++) a[i] = As[kk][ty * 4 + i];
            #pragma unroll
            for (int j = 0; j < 4; j++) b[j] = Bs[kk][tx * 4 + j];
            #pragma unroll
            for (int i = 0; i < 4; i++)
                #pragma unroll
                for (int j = 0; j < 4; j++) acc[i][j] += a[i] * b[j];
        }
        __syncthreads();
    }
    #pragma unroll
    for (int i = 0; i < 4; i++) {
        int row = m0 + ty * 4 + i;
        #pragma unroll
        for (int j = 0; j < 4; j++) {
            int col = n0 + tx * 4 + j;
            float bv;
            if (bias_mode == 0)
                bv = (col < 192) ? bias0[col] : ((col < 384) ? 0.f : bias1[col - 384]);
            else
                bv = bias0[col];
            C[(size_t)row * N + col] = acc[i][j] + bv;
        }
    }
}

// ---------------- Kernel C: fused depthwise(k,v) + norms + attention + PV ----------------
// One wave (64 threads) per pixel. Lane l owns channels 3l,3l+1,3l+2.
__global__ __launch_bounds__(64)
void fused_attn_kernel(const float* __restrict__ qkv, const float* __restrict__ deform,
                       const float* __restrict__ scale, const float* __restrict__ rb,
                       float* __restrict__ outp)
{
    __shared__ float klds[1728];
    __shared__ float vlds[1728];
    __shared__ float logit_l[54];
    __shared__ float wlds[54];
    __shared__ float qnl[6];

    int p = blockIdx.x;
    int b = p / (96 * 96);
    int rem = p - b * 96 * 96;
    int y = rem / 96, x = rem - (rem / 96) * 96;
    int l = threadIdx.x;
    const float* row = qkv + (size_t)p * QKVN;

    // ---- phase 1: depthwise for k and v (same effective kernel W = deform + I) ----
    #pragma unroll
    for (int j = 0; j < 3; j++) {
        int c = 3 * l + j;
        float kin[9], vin[9];
        #pragma unroll
        for (int pos = 0; pos < 9; pos++) {
            int dy = pos / 3 - 1, dx = pos % 3 - 1;
            int yy = y + dy, xx = x + dx;
            bool ok = (yy >= 0) && (yy < 96) && (xx >= 0) && (xx < 96);
            const float* nrow = qkv + (size_t)((b * 96 + yy) * 96 + xx) * QKVN;
            kin[pos] = ok ? nrow[192 + c] : 0.f;
            vin[pos] = ok ? nrow[384 + c] : 0.f;
        }
        float ko[9], vo[9];
        #pragma unroll
        for (int t = 0; t < 9; t++) { ko[t] = 0.f; vo[t] = 0.f; }
        #pragma unroll
        for (int pos = 0; pos < 9; pos++) {
            const float* wp = deform + pos * 1728 + c * 9;
            float kv = kin[pos], vv = vin[pos];
            #pragma unroll
            for (int t = 0; t < 9; t++) {
                float w = wp[t];
                if (t == pos) w += 1.f;
                ko[t] += kv * w;
                vo[t] += vv * w;
            }
        }
        #pragma unroll
        for (int t = 0; t < 9; t++) {
            klds[c * 9 + t] = ko[t];
            vlds[c * 9 + t] = vo[t];
        }
    }
    // ---- q norms (per head) ----
    if (l < 6) {
        float s = 0.f;
        for (int u = 0; u < 32; u++) { float qv = row[l * 32 + u]; s += qv * qv; }
        qnl[l] = rsqrtf(fmaxf(s, EPS));
    }
    __syncthreads();
    // ---- per (head, tap): k norm, q.k, logit ----
    if (l < 54) {
        int he = l / 9, t = l - he * 9;
        float kn = 0.f, qk = 0.f;
        #pragma unroll
        for (int u = 0; u < 32; u++) {
            float kv = klds[(he * 32 + u) * 9 + t];
            kn += kv * kv;
            qk += row[he * 32 + u] * kv;
        }
        int dy = t / 3 - 1, dx = t % 3 - 1;
        bool ok = (y + dy >= 0) && (y + dy < 96) && (x + dx >= 0) && (x + dx < 96);
        float logit = expf(scale[he]) * qnl[he] * qk * rsqrtf(fmaxf(kn, EPS));
        logit += (ok ? 0.f : -100.f) + rb[he * 9 + t];
        logit_l[l] = logit;
    }
    __syncthreads();
    if (l < 54) {
        int he = l / 9;
        float m = -1e30f;
        #pragma unroll
        for (int t2 = 0; t2 < 9; t2++) m = fmaxf(m, logit_l[he * 9 + t2]);
        float s = 0.f;
        #pragma unroll
        for (int t2 = 0; t2 < 9; t2++) s += expf(logit_l[he * 9 + t2] - m);
        wlds[l] = expf(logit_l[l] - m) / s;
    }
    __syncthreads();
    // ---- PV: out[c] = sum_t w[head(c),t] * v[c,t] ----
    #pragma unroll
    for (int j = 0; j < 3; j++) {
        int c = 3 * l + j;
        int he = c >> 5;
        float o = 0.f;
        #pragma unroll
        for (int t = 0; t < 9; t++) o += wlds[he * 9 + t] * vlds[c * 9 + t];
        outp[(size_t)p * CCH + c] = o;
    }
}

extern "C" void kernel_launch(void* const* d_in, const int* in_sizes, int n_in,
                              void* d_out, int out_size, void* d_ws, size_t ws_size,
                              hipStream_t stream) {
    const float* x       = (const float*)d_in[0];
    const float* qkv_w   = (const float*)d_in[1];
    const float* q_bias  = (const float*)d_in[2];
    const float* v_bias  = (const float*)d_in[3];
    const float* deform  = (const float*)d_in[4];
    const float* scale   = (const float*)d_in[5];
    const float* cpb_w1  = (const float*)d_in[6];
    const float* cpb_b1  = (const float*)d_in[7];
    const float* cpb_w2  = (const float*)d_in[8];
    const float* proj_w  = (const float*)d_in[9];
    const float* proj_b  = (const float*)d_in[10];
    float* out = (float*)d_out;

    float* ws = (float*)d_ws;
    float* rb = ws;                                // 64 floats (54 used)
    float* qkv = ws + 64;                          // PIX * 576
    float* attn = qkv + (size_t)PIX * QKVN;        // PIX * 192

    relbias_kernel<<<1, 512, 0, stream>>>(cpb_w1, cpb_b1, cpb_w2, rb);
    gemm_bias_kernel<<<dim3(QKVN / 64, PIX / 64), 256, 0, stream>>>(
        x, qkv_w, qkv, PIX, QKVN, CCH, q_bias, v_bias, 0);
    fused_attn_kernel<<<PIX, 64, 0, stream>>>(qkv, deform, scale, rb, attn);
    gemm_bias_kernel<<<dim3(CCH / 64, PIX / 64), 256, 0, stream>>>(
        attn, proj_w, out, PIX, CCH, CCH, proj_b, nullptr, 1);
}

// Round 2
// 340.385 us; speedup vs baseline: 1.8629x; 1.8629x over previous
//
#include <hip/hip_runtime.h>
#include <math.h>

#define EPS 1.55e-05f
#define PIXELS 36864   // 4*96*96
#define IMG 9216       // 96*96
#define CCH 192

// ---------------- Kernel A: relative position bias (6 heads x 9 taps) ----------------
__global__ __launch_bounds__(512)
void relbias_kernel(const float* __restrict__ w1, const float* __restrict__ b1,
                    const float* __restrict__ w2, float* __restrict__ rb)
{
    __shared__ float hid[9][512];
    int i = threadIdx.x;
    const float s0 = -0.7739760316291208f, s2 = 0.7739760316291208f;
    float sv[3]; sv[0] = s0; sv[1] = 0.f; sv[2] = s2;
    float w1a = w1[i], w1b = w1[512 + i], bb = b1[i];
    #pragma unroll
    for (int j = 0; j < 9; j++) {
        float t0 = sv[j / 3], t1 = sv[j % 3];
        hid[j][i] = fmaxf(t0 * w1a + t1 * w1b + bb, 0.f);
    }
    __syncthreads();
    if (i < 54) {
        int he = i / 9, t = i % 9, j = 8 - t;   // bias[::-1] then transpose
        float acc = 0.f;
        for (int u = 0; u < 512; u++) acc += hid[j][u] * w2[u * 6 + he];
        rb[he * 9 + t] = 16.f / (1.f + expf(-acc));
    }
}

// ---------------- GEMM1: qkv^T = (x @ qkv_w + bias)^T  (store transposed) -------------
// A: PIXELS x 192, B: 192 x 576, CT: 576 x PIXELS
__global__ __launch_bounds__(256)
void gemm_qkvT_kernel(const float* __restrict__ A, const float* __restrict__ B,
                      float* __restrict__ CT,
                      const float* __restrict__ q_bias, const float* __restrict__ v_bias)
{
    const int M = PIXELS, N = 576, K = 192;
    __shared__ float As[32][64];
    __shared__ float Bs[32][64];
    int tid = threadIdx.x;
    int m0 = blockIdx.y * 64, n0 = blockIdx.x * 64;
    int tx = tid & 15, ty = tid >> 4;
    float acc[4][4];
    #pragma unroll
    for (int i = 0; i < 4; i++)
        #pragma unroll
        for (int j = 0; j < 4; j++) acc[i][j] = 0.f;

    for (int k0 = 0; k0 < K; k0 += 32) {
        int ar = tid >> 3, ac4 = (tid & 7) * 4;
        #pragma unroll
        for (int rr = 0; rr < 2; rr++) {
            float4 v = *reinterpret_cast<const float4*>(&A[(size_t)(m0 + ar + rr * 32) * K + k0 + ac4]);
            As[ac4 + 0][ar + rr * 32] = v.x;
            As[ac4 + 1][ar + rr * 32] = v.y;
            As[ac4 + 2][ar + rr * 32] = v.z;
            As[ac4 + 3][ar + rr * 32] = v.w;
        }
        int br = tid >> 4, bc4 = (tid & 15) * 4;
        #pragma unroll
        for (int rr = 0; rr < 2; rr++)
            *reinterpret_cast<float4*>(&Bs[br + rr * 16][bc4]) =
                *reinterpret_cast<const float4*>(&B[(size_t)(k0 + br + rr * 16) * N + n0 + bc4]);
        __syncthreads();
        #pragma unroll
        for (int kk = 0; kk < 32; kk++) {
            float a[4], b[4];
            #pragma unroll
            for (int i = 0; i < 4; i++) a[i] = As[kk][ty * 4 + i];
            #pragma unroll
            for (int j = 0; j < 4; j++) b[j] = Bs[kk][tx * 4 + j];
            #pragma unroll
            for (int i = 0; i < 4; i++)
                #pragma unroll
                for (int j = 0; j < 4; j++) acc[i][j] += a[i] * b[j];
        }
        __syncthreads();
    }
    #pragma unroll
    for (int j = 0; j < 4; j++) {
        int col = n0 + tx * 4 + j;
        float bv = (col < 192) ? q_bias[col] : ((col < 384) ? 0.f : v_bias[col - 384]);
        float4 v;
        v.x = acc[0][j] + bv; v.y = acc[1][j] + bv;
        v.z = acc[2][j] + bv; v.w = acc[3][j] + bv;
        *reinterpret_cast<float4*>(&CT[(size_t)col * M + m0 + ty * 4]) = v;
    }
}

// ---------------- Fused: depthwise(k,v) + cosine attention + PV -----------------------
// One wave per (head, 8x8 pixel tile). Lane = pixel. Weights are wave-uniform (SGPR).
__global__ __launch_bounds__(64)
void fused2_kernel(const float* __restrict__ qkvT, const float* __restrict__ deform,
                   const float* __restrict__ scale, const float* __restrict__ rb,
                   float* __restrict__ attnT)
{
    int id = blockIdx.x;              // 4 batches * 144 tiles * 6 heads
    int he = id % 6;
    int t144 = (id / 6) % 144;
    int b = id / (6 * 144);
    int tx0 = (t144 % 12) * 8, ty0 = (t144 / 12) * 8;
    int l = threadIdx.x;
    int X = tx0 + (l & 7), Y = ty0 + (l >> 3);
    int pimg = Y * 96 + X;
    size_t ibase = (size_t)b * IMG;

    int off[9];
    unsigned okm = 0;
    #pragma unroll
    for (int pos = 0; pos < 9; pos++) {
        int dy = pos / 3 - 1, dx = pos % 3 - 1;
        int yy = Y + dy, xx = X + dx;
        bool ok = (yy >= 0) && (yy < 96) && (xx >= 0) && (xx < 96);
        okm |= (ok ? 1u : 0u) << pos;
        off[pos] = ok ? (yy * 96 + xx) : pimg;
    }

    float qk[9], kn[9];
    #pragma unroll
    for (int t = 0; t < 9; t++) { qk[t] = 0.f; kn[t] = 0.f; }
    float qn2 = 0.f;

    // ---- pass 1: k depthwise + per-head reductions (register accumulation) ----
    for (int ci = 0; ci < 32; ci++) {
        int c = he * 32 + ci;
        const float* qrow = qkvT + (size_t)c * PIXELS + ibase;
        const float* krow = qkvT + (size_t)(192 + c) * PIXELS + ibase;
        float q = qrow[pimg];
        qn2 = fmaf(q, q, qn2);
        float kin[9];
        #pragma unroll
        for (int pos = 0; pos < 9; pos++)
            kin[pos] = ((okm >> pos) & 1) ? krow[off[pos]] : 0.f;
        float ktap[9];
        #pragma unroll
        for (int t = 0; t < 9; t++) ktap[t] = kin[t];   // identity (static kernel) part
        #pragma unroll
        for (int pos = 0; pos < 9; pos++) {
            const float* wr = deform + ((size_t)pos * CCH + c) * 9;   // wave-uniform
            #pragma unroll
            for (int t = 0; t < 9; t++) ktap[t] = fmaf(kin[pos], wr[t], ktap[t]);
        }
        #pragma unroll
        for (int t = 0; t < 9; t++) {
            qk[t] = fmaf(q, ktap[t], qk[t]);
            kn[t] = fmaf(ktap[t], ktap[t], kn[t]);
        }
    }

    // ---- softmax (fully lane-local) ----
    float qn = rsqrtf(fmaxf(qn2, EPS));
    float es = expf(scale[he]);
    float w[9];
    float m = -1e30f;
    #pragma unroll
    for (int t = 0; t < 9; t++) {
        float lg = es * qn * qk[t] * rsqrtf(fmaxf(kn[t], EPS));
        lg += (((okm >> t) & 1) ? 0.f : -100.f) + rb[he * 9 + t];
        w[t] = lg;
        m = fmaxf(m, lg);
    }
    float ssum = 0.f;
    #pragma unroll
    for (int t = 0; t < 9; t++) { w[t] = expf(w[t] - m); ssum += w[t]; }
    float inv = 1.f / ssum;
    #pragma unroll
    for (int t = 0; t < 9; t++) w[t] *= inv;

    // ---- pass 2: v depthwise folded through softmax weights ----
    for (int ci = 0; ci < 32; ci++) {
        int c = he * 32 + ci;
        const float* vrow = qkvT + (size_t)(384 + c) * PIXELS + ibase;
        float vin[9];
        #pragma unroll
        for (int pos = 0; pos < 9; pos++)
            vin[pos] = ((okm >> pos) & 1) ? vrow[off[pos]] : 0.f;
        float acc = 0.f;
        #pragma unroll
        for (int pos = 0; pos < 9; pos++) {
            const float* wr = deform + ((size_t)pos * CCH + c) * 9;   // wave-uniform
            float sp = w[pos];   // identity part of v kernel
            #pragma unroll
            for (int t = 0; t < 9; t++) sp = fmaf(w[t], wr[t], sp);
            acc = fmaf(vin[pos], sp, acc);
        }
        attnT[(size_t)c * PIXELS + ibase + pimg] = acc;
    }
}

// ---------------- GEMM2: out = attn^T^T @ proj_w + proj_b ----------------------------
// AT: 192 x PIXELS (k-major), B: 192 x 192, C: PIXELS x 192 (normal layout)
__global__ __launch_bounds__(256)
void gemm_proj_kernel(const float* __restrict__ AT, const float* __restrict__ B,
                      float* __restrict__ C, const float* __restrict__ bias)
{
    const int M = PIXELS, N = 192, K = 192;
    __shared__ float As[32][64];   // [k][m]
    __shared__ float Bs[32][64];   // [k][n]
    int tid = threadIdx.x;
    int m0 = blockIdx.y * 64, n0 = blockIdx.x * 64;
    int tx = tid & 15, ty = tid >> 4;
    float acc[4][4];
    #pragma unroll
    for (int i = 0; i < 4; i++)
        #pragma unroll
        for (int j = 0; j < 4; j++) acc[i][j] = 0.f;

    for (int k0 = 0; k0 < K; k0 += 32) {
        int r = tid >> 4, c4 = (tid & 15) * 4;
        #pragma unroll
        for (int rr = 0; rr < 2; rr++) {
            *reinterpret_cast<float4*>(&As[r + rr * 16][c4]) =
                *reinterpret_cast<const float4*>(&AT[(size_t)(k0 + r + rr * 16) * M + m0 + c4]);
            *reinterpret_cast<float4*>(&Bs[r + rr * 16][c4]) =
                *reinterpret_cast<const float4*>(&B[(size_t)(k0 + r + rr * 16) * N + n0 + c4]);
        }
        __syncthreads();
        #pragma unroll
        for (int kk = 0; kk < 32; kk++) {
            float a[4], b[4];
            #pragma unroll
            for (int i = 0; i < 4; i++) a[i] = As[kk][ty * 4 + i];
            #pragma unroll
            for (int j = 0; j < 4; j++) b[j] = Bs[kk][tx * 4 + j];
            #pragma unroll
            for (int i = 0; i < 4; i++)
                #pragma unroll
                for (int j = 0; j < 4; j++) acc[i][j] += a[i] * b[j];
        }
        __syncthreads();
    }
    #pragma unroll
    for (int i = 0; i < 4; i++) {
        int row = m0 + ty * 4 + i;
        #pragma unroll
        for (int j = 0; j < 4; j++) {
            int col = n0 + tx * 4 + j;
            C[(size_t)row * N + col] = acc[i][j] + bias[col];
        }
    }
}

extern "C" void kernel_launch(void* const* d_in, const int* in_sizes, int n_in,
                              void* d_out, int out_size, void* d_ws, size_t ws_size,
                              hipStream_t stream) {
    const float* x       = (const float*)d_in[0];
    const float* qkv_w   = (const float*)d_in[1];
    const float* q_bias  = (const float*)d_in[2];
    const float* v_bias  = (const float*)d_in[3];
    const float* deform  = (const float*)d_in[4];
    const float* scale   = (const float*)d_in[5];
    const float* cpb_w1  = (const float*)d_in[6];
    const float* cpb_b1  = (const float*)d_in[7];
    const float* cpb_w2  = (const float*)d_in[8];
    const float* proj_w  = (const float*)d_in[9];
    const float* proj_b  = (const float*)d_in[10];
    float* out = (float*)d_out;

    float* ws = (float*)d_ws;
    float* rb    = ws;                                  // 64 floats (54 used)
    float* qkvT  = ws + 64;                             // 576 * PIXELS
    float* attnT = qkvT + (size_t)576 * PIXELS;         // 192 * PIXELS

    relbias_kernel<<<1, 512, 0, stream>>>(cpb_w1, cpb_b1, cpb_w2, rb);
    gemm_qkvT_kernel<<<dim3(576 / 64, PIXELS / 64), 256, 0, stream>>>(
        x, qkv_w, qkvT, q_bias, v_bias);
    fused2_kernel<<<4 * 144 * 6, 64, 0, stream>>>(qkvT, deform, scale, rb, attnT);
    gemm_proj_kernel<<<dim3(192 / 64, PIXELS / 64), 256, 0, stream>>>(
        attnT, proj_w, out, proj_b);
}